// Round 7
// baseline (305.815 us; speedup 1.0000x reference)
//
#include <hip/hip_runtime.h>

#define NPG  256   // nodes per graph
#define EPG  4096  // edges per graph
#define FDIM 128
#define KTOP 30

// 256 threads/block, thread t owns node t (round-0 structure: the only shape
// that allocates spill-free — VGPR budget 256, round 0 used 116).
// Rounds 1-5: at 512 threads the backend pins VGPR=128 and spills 11-60 MB of
// scratch; extra waves never raised VALUBusy (barrier-locked). So: 256 threads
// + ILP instead of TLP.
// Round 6 lesson: srclist order from atomicAdd arrival is nondeterministic
// across graph replays -> fp summation reorder -> top-K boundary flip ->
// post-timing divergence. Fix: per-node insertion sort of the in-segment
// (ascending src) right after the edge build; sums become bit-deterministic.
__global__ __launch_bounds__(256, 1)
void dgcnn_fused(const float* __restrict__ node_feat,
                 const int* __restrict__ srcv, const int* __restrict__ dstv,
                 const int* __restrict__ degs,
                 const float* __restrict__ W0, const float* __restrict__ b0,
                 const float* __restrict__ W1, const float* __restrict__ b1,
                 const float* __restrict__ W2, const float* __restrict__ b2,
                 const float* __restrict__ W3, const float* __restrict__ b3,
                 const float* __restrict__ cw1, const float* __restrict__ cb1,
                 const float* __restrict__ cw2, const float* __restrict__ cb2,
                 const float* __restrict__ ow,  const float* __restrict__ ob,
                 float* __restrict__ outp)
{
    __shared__ float Ybuf[NPG * 33];   // 33792 B; stride 33 -> bank (n+c)%32
    __shared__ int   srclist[EPG];     // 16384 B; in-edges grouped by dst; reused by tail
    __shared__ int   offs[NPG];
    __shared__ int   cnt [NPG];
    __shared__ int   degl[NPG];
    __shared__ float invd[NPG];
    __shared__ float keys[NPG];
    __shared__ int   wsum[4];
    // total ~55.3 KB

    const int g = blockIdx.x;
    const int t = threadIdx.x;

    // ================= degrees + wave-shuffle prefix scan (2 barriers) =======
    const int dn = degs[g * NPG + t];
    degl[t] = dn;
    cnt[t]  = 0;
    invd[t] = 1.0f / (float)(dn + 1);
    {
        int v = dn;
        const int lane = t & 63;
        #pragma unroll
        for (int off = 1; off < 64; off <<= 1) {
            int u = __shfl_up(v, off);
            if (lane >= off) v += u;
        }
        if (lane == 63) wsum[t >> 6] = v;   // wave totals (waves 0..3)
        __syncthreads();
        const int w = t >> 6;
        int base = 0;
        #pragma unroll
        for (int i = 0; i < 4; i++) base += (i < w) ? wsum[i] : 0;
        offs[t] = base + v - dn;   // exclusive prefix of in-degrees
        __syncthreads();
    }

    // ================= edge-list build (counting sort by dst) ================
    {
        const int* sg = srcv + g * EPG;
        const int* dg = dstv + g * EPG;
        #pragma unroll
        for (int i = 0; i < EPG / NPG; i++) {
            int e  = t + i * NPG;
            int ss = sg[e] & (NPG - 1);   // graphs are 256-node aligned
            int dd = dg[e] & (NPG - 1);
            int p  = atomicAdd(&cnt[dd], 1);
            srclist[offs[dd] + p] = ss;
        }
    }
    __syncthreads();   // srclist fully scattered (writes land in other segments)

    const float iv = invd[t];
    const int   o  = offs[t];
    const int   d  = degl[t];

    // canonicalize in-edge order: ascending src (duplicates commute exactly).
    // Own segment only -> no cross-thread hazard; phase-0's trailing barrier
    // orders this before any aggregation reads.
    for (int i = 1; i < d; i++) {
        int key = srclist[o + i];
        int j = i - 1;
        while (j >= 0 && srclist[o + j] > key) {
            srclist[o + j + 1] = srclist[o + j];
            --j;
        }
        srclist[o + j + 1] = key;
    }

    // ================= phase 0: y0 = node_feat @ W0 (register-streamed) ======
    // Full 128-float row streamed through 8 named float4s (by-value into the
    // FMA helper: proven spill-clean codegen). acc[32]+8xfloat4 ~ 110 live
    // VGPRs -- fits the 256 budget at 256 threads. No LDS, no barriers here.
    {
        const float4* nf4 = (const float4*)(node_feat + ((size_t)g * NPG + t) * FDIM);
        float acc[32];
        #pragma unroll
        for (int c = 0; c < 32; c++) acc[c] = 0.f;

        auto fma4 = [&](float4 r, int kbase) {   // r by value: stays in VGPRs
            const float* w0 = W0 + (kbase + 0) * 32;
            const float* w1 = W0 + (kbase + 1) * 32;
            const float* w2 = W0 + (kbase + 2) * 32;
            const float* w3 = W0 + (kbase + 3) * 32;   // wave-uniform -> scalar
            #pragma unroll
            for (int c = 0; c < 32; c++) {
                float a = acc[c];
                a = fmaf(r.x, w0[c], a);
                a = fmaf(r.y, w1[c], a);
                a = fmaf(r.z, w2[c], a);
                a = fmaf(r.w, w3[c], a);
                acc[c] = a;
            }
        };

        float4 A0 = nf4[0], A1 = nf4[1], A2 = nf4[2], A3 = nf4[3];
        float4 B0 = nf4[4], B1 = nf4[5], B2 = nf4[6], B3 = nf4[7];
        fma4(A0,   0); fma4(A1,   4); fma4(A2,   8); fma4(A3,  12);
        A0 = nf4[8];  A1 = nf4[9];  A2 = nf4[10]; A3 = nf4[11];
        fma4(B0,  16); fma4(B1,  20); fma4(B2,  24); fma4(B3,  28);
        B0 = nf4[12]; B1 = nf4[13]; B2 = nf4[14]; B3 = nf4[15];
        fma4(A0,  32); fma4(A1,  36); fma4(A2,  40); fma4(A3,  44);
        A0 = nf4[16]; A1 = nf4[17]; A2 = nf4[18]; A3 = nf4[19];
        fma4(B0,  48); fma4(B1,  52); fma4(B2,  56); fma4(B3,  60);
        B0 = nf4[20]; B1 = nf4[21]; B2 = nf4[22]; B3 = nf4[23];
        fma4(A0,  64); fma4(A1,  68); fma4(A2,  72); fma4(A3,  76);
        A0 = nf4[24]; A1 = nf4[25]; A2 = nf4[26]; A3 = nf4[27];
        fma4(B0,  80); fma4(B1,  84); fma4(B2,  88); fma4(B3,  92);
        B0 = nf4[28]; B1 = nf4[29]; B2 = nf4[30]; B3 = nf4[31];
        fma4(A0,  96); fma4(A1, 100); fma4(A2, 104); fma4(A3, 108);
        fma4(B0, 112); fma4(B1, 116); fma4(B2, 120); fma4(B3, 124);

        #pragma unroll
        for (int c = 0; c < 32; c++) Ybuf[t * 33 + c] = acc[c];
        __syncthreads();   // y0 visible; segment sorts also complete here
    }

    // pooled = y[t] + sum_{in-edges} y[src]; 4 neighbors in flight.
    // Adds stay in exact (sorted) srclist order -> deterministic.
    auto agg = [&](float (&h)[32]) {
        const float* self = &Ybuf[t * 33];
        #pragma unroll
        for (int c = 0; c < 32; c++) h[c] = self[c];
        int j = 0;
        for (; j + 4 <= d; j += 4) {
            const int a0 = srclist[o + j + 0];
            const int a1 = srclist[o + j + 1];
            const int a2 = srclist[o + j + 2];
            const int a3 = srclist[o + j + 3];
            const float* r0 = &Ybuf[a0 * 33];
            const float* r1 = &Ybuf[a1 * 33];
            const float* r2 = &Ybuf[a2 * 33];
            const float* r3 = &Ybuf[a3 * 33];
            #pragma unroll
            for (int c = 0; c < 32; c++) h[c] += r0[c];
            #pragma unroll
            for (int c = 0; c < 32; c++) h[c] += r1[c];
            #pragma unroll
            for (int c = 0; c < 32; c++) h[c] += r2[c];
            #pragma unroll
            for (int c = 0; c < 32; c++) h[c] += r3[c];
        }
        for (; j < d; j++) {
            const float* yr = &Ybuf[srclist[o + j] * 33];
            #pragma unroll
            for (int c = 0; c < 32; c++) h[c] += yr[c];
        }
    };
    auto act = [&](float (&h)[32], const float* bb) {
        #pragma unroll
        for (int c = 0; c < 32; c++) h[c] = tanhf((h[c] + bb[c]) * iv);
    };
    // y_next = h @ Wn (32x32) -> Ybuf (barrier-protected overwrite)
    auto matml = [&](const float (&h)[32], const float* Wn) {
        float a[32];
        #pragma unroll
        for (int c = 0; c < 32; c++) a[c] = 0.f;
        #pragma unroll
        for (int k = 0; k < 32; k++) {
            const float* wr = Wn + k * 32;   // wave-uniform -> scalar loads
            const float  hk = h[k];
            #pragma unroll
            for (int c = 0; c < 32; c++) a[c] = fmaf(hk, wr[c], a[c]);
        }
        __syncthreads();   // all agg reads of Ybuf complete
        #pragma unroll
        for (int c = 0; c < 32; c++) Ybuf[t * 33 + c] = a[c];
        __syncthreads();
    };

    // ================= 4 GNN layers =================
    float h1[32], h2[32], h3[32];
    agg(h1); act(h1, b0); matml(h1, W1);
    agg(h2); act(h2, b1); matml(h2, W2);
    agg(h3); act(h3, b2);
    {   // layer 3 projection: y3 = h3 @ W3  (W3 is 32x1)
        float a3 = 0.f;
        #pragma unroll
        for (int k = 0; k < 32; k++) a3 = fmaf(h3[k], W3[k], a3);
        __syncthreads();   // all layer-2 agg reads of Ybuf complete
        Ybuf[t * 33] = a3;
        __syncthreads();
    }
    float kv;
    {   // layer 3 aggregate (1-wide) + activation -> sort key; 4-wide unroll
        float s = Ybuf[t * 33];
        int j = 0;
        for (; j + 4 <= d; j += 4) {
            const int a0 = srclist[o + j + 0];
            const int a1 = srclist[o + j + 1];
            const int a2 = srclist[o + j + 2];
            const int a3i = srclist[o + j + 3];
            s += Ybuf[a0 * 33];
            s += Ybuf[a1 * 33];
            s += Ybuf[a2 * 33];
            s += Ybuf[a3i * 33];
        }
        for (; j < d; j++) s += Ybuf[srclist[o + j] * 33];
        kv = tanhf((s + b3[0]) * iv);
        keys[t] = kv;
    }
    __syncthreads();

    // ================= sortpool: rank-based top-K (jax tie-break: lower idx) ==
    int rank = 0;
    #pragma unroll 4
    for (int j = 0; j < NPG; j++) {
        float vj = keys[j];
        rank += ((vj > kv) || ((vj == kv) && (j < t))) ? 1 : 0;
    }

    // ================= export selected Z rows, then conv tail ================
    float* sp    = (float*)srclist;   // 2910 floats (srclist dead from here)
    float* x1    = sp + 30 * 97;      // 480
    float* xp    = x1 + 480;          // 240
    float* dense = xp + 240;          // 352  (total 3982 floats <= 4096)

    if (rank < KTOP) {
        float* dp = sp + rank * 97;
        #pragma unroll
        for (int c = 0; c < 32; c++) dp[c]      = h1[c];
        #pragma unroll
        for (int c = 0; c < 32; c++) dp[32 + c] = h2[c];
        #pragma unroll
        for (int c = 0; c < 32; c++) dp[64 + c] = h3[c];
        dp[96] = kv;
    }
    __syncthreads();

    // conv1: kernel width 97, stride 97 -> per-row dot; out [16][30], relu
    for (int idx = t; idx < 480; idx += 256) {
        int k = idx >> 4, c = idx & 15;
        float s = cb1[c];
        for (int dd = 0; dd < 97; dd++) s = fmaf(sp[k * 97 + dd], cw1[c * 97 + dd], s);
        x1[c * 30 + k] = fmaxf(s, 0.f);
    }
    __syncthreads();
    // maxpool1d(2,2) -> [16][15]
    for (int idx = t; idx < 240; idx += 256) {
        int c = idx / 15, k = idx - c * 15;
        xp[idx] = fmaxf(x1[c * 30 + 2 * k], x1[c * 30 + 2 * k + 1]);
    }
    __syncthreads();
    // conv2: [32][16][5] VALID over 15 -> [32][11], relu; dense idx = c*11+j
    for (int idx = t; idx < 352; idx += 256) {
        int c = idx / 11, j = idx - c * 11;
        float s = cb2[c];
        for (int i2 = 0; i2 < 16; i2++) {
            #pragma unroll
            for (int tt = 0; tt < 5; tt++)
                s = fmaf(xp[i2 * 15 + j + tt], cw2[(c * 16 + i2) * 5 + tt], s);
        }
        dense[idx] = fmaxf(s, 0.f);
    }
    __syncthreads();
    // output: relu(relu(dense @ out_w + out_b)) -> [2]
    if (t < 64) {
        float a0 = 0.f, a1 = 0.f;
        for (int dd = t; dd < 352; dd += 64) {
            float v = dense[dd];
            a0 = fmaf(v, ow[dd * 2],     a0);
            a1 = fmaf(v, ow[dd * 2 + 1], a1);
        }
        #pragma unroll
        for (int off2 = 32; off2 > 0; off2 >>= 1) {
            a0 += __shfl_down(a0, off2);
            a1 += __shfl_down(a1, off2);
        }
        if (t == 0) {
            outp[g * 2 + 0] = fmaxf(a0 + ob[0], 0.f);
            outp[g * 2 + 1] = fmaxf(a1 + ob[1], 0.f);
        }
    }
}

extern "C" void kernel_launch(void* const* d_in, const int* in_sizes, int n_in,
                              void* d_out, int out_size, void* d_ws, size_t ws_size,
                              hipStream_t stream) {
    const float* node_feat = (const float*)d_in[0];
    const int*   src       = (const int*)  d_in[1];
    const int*   dst       = (const int*)  d_in[2];
    const int*   degsp     = (const int*)  d_in[3];
    const float* W0 = (const float*)d_in[4];
    const float* b0 = (const float*)d_in[5];
    const float* W1 = (const float*)d_in[6];
    const float* b1 = (const float*)d_in[7];
    const float* W2 = (const float*)d_in[8];
    const float* b2 = (const float*)d_in[9];
    const float* W3 = (const float*)d_in[10];
    const float* b3 = (const float*)d_in[11];
    const float* cw1 = (const float*)d_in[12];
    const float* cb1 = (const float*)d_in[13];
    const float* cw2 = (const float*)d_in[14];
    const float* cb2 = (const float*)d_in[15];
    const float* ow  = (const float*)d_in[16];
    const float* ob  = (const float*)d_in[17];

    dgcnn_fused<<<dim3(256), dim3(256), 0, stream>>>(
        node_feat, src, dst, degsp,
        W0, b0, W1, b1, W2, b2, W3, b3,
        cw1, cb1, cw2, cb2, ow, ob, (float*)d_out);
}

// Round 8
// 227.332 us; speedup vs baseline: 1.3452x; 1.3452x over previous
//
#include <hip/hip_runtime.h>

#define NPG  256   // nodes per graph
#define EPG  4096  // edges per graph
#define FDIM 128
#define KTOP 30

// 256 threads/block, thread t owns node t — round-0 structure (92 us proven,
// no spill: VGPR budget 256, uses ~150). Lessons kept from rounds 1-7:
//  * 512-thread shapes get VGPR pinned to 128 -> scratch spill = runtime (r1-5)
//  * srclist order from atomicAdd arrival is replay-nondeterministic -> fp sum
//    reorder -> top-K boundary flip (r6). Fixed via a rank-based STABLE
//    reorder (independent reads, ~4 us) instead of r7's insertion sort
//    (dependent divergent LDS chain, ~80 us of the r7 regression).
//  * shuffle prefix scan (2 barriers) and 4-wide agg unroll kept from r7.
//  * conv-tail weights staged into dead Ybuf -> LDS reads instead of global
//    gathers in the 97/80-deep inner loops.
__global__ __launch_bounds__(256, 1)
void dgcnn_fused(const float* __restrict__ node_feat,
                 const int* __restrict__ srcv, const int* __restrict__ dstv,
                 const int* __restrict__ degs,
                 const float* __restrict__ W0, const float* __restrict__ b0,
                 const float* __restrict__ W1, const float* __restrict__ b1,
                 const float* __restrict__ W2, const float* __restrict__ b2,
                 const float* __restrict__ W3, const float* __restrict__ b3,
                 const float* __restrict__ cw1, const float* __restrict__ cb1,
                 const float* __restrict__ cw2, const float* __restrict__ cb2,
                 const float* __restrict__ ow,  const float* __restrict__ ob,
                 float* __restrict__ outp)
{
    __shared__ float Ybuf[NPG * 33];   // 33792 B; stride 33 -> bank (n+c)%32
    __shared__ int   srclist[EPG];     // 16384 B; in-edges grouped by dst; reused by tail
    __shared__ int   offs[NPG];
    __shared__ int   cnt [NPG];
    __shared__ int   degl[NPG];
    __shared__ float invd[NPG];
    __shared__ float keys[NPG];
    __shared__ int   wsum[4];
    // total ~54 KB

    const int g = blockIdx.x;
    const int t = threadIdx.x;

    // ================= degrees + wave-shuffle prefix scan (2 barriers) =======
    const int dn = degs[g * NPG + t];
    degl[t] = dn;
    cnt[t]  = 0;
    invd[t] = 1.0f / (float)(dn + 1);
    {
        int v = dn;
        const int lane = t & 63;
        #pragma unroll
        for (int off = 1; off < 64; off <<= 1) {
            int u = __shfl_up(v, off);
            if (lane >= off) v += u;
        }
        if (lane == 63) wsum[t >> 6] = v;   // wave totals (waves 0..3)
        __syncthreads();
        const int w = t >> 6;
        int base = 0;
        #pragma unroll
        for (int i = 0; i < 4; i++) base += (i < w) ? wsum[i] : 0;
        offs[t] = base + v - dn;   // exclusive prefix of in-degrees
        __syncthreads();
    }

    // ================= edge-list build (counting sort by dst) ================
    {
        const int* sg = srcv + g * EPG;
        const int* dg = dstv + g * EPG;
        #pragma unroll
        for (int i = 0; i < EPG / NPG; i++) {
            int e  = t + i * NPG;
            int ss = sg[e] & (NPG - 1);   // graphs are 256-node aligned
            int dd = dg[e] & (NPG - 1);
            int p  = atomicAdd(&cnt[dd], 1);
            srclist[offs[dd] + p] = ss;
        }
    }
    __syncthreads();   // srclist fully scattered

    const float iv = invd[t];
    const int   o  = offs[t];
    const int   d  = degl[t];

    // ======= deterministic stable reorder of own segment (ascending src) =====
    // rank-based: all reads independent (pipelined), no dependent LDS chain,
    // no data-dependent inner trip counts. Thread-local (own segment + own
    // tmp slice of Ybuf) -> no barriers; phase-0's first barrier orders the
    // Ybuf reuse.
    {
        int* tmp = (int*)Ybuf;
        for (int i = 0; i < d; i++) {
            const int key = srclist[o + i];
            int r = 0, j = 0;
            for (; j + 4 <= d; j += 4) {
                const int v0 = srclist[o + j + 0];
                const int v1 = srclist[o + j + 1];
                const int v2 = srclist[o + j + 2];
                const int v3 = srclist[o + j + 3];
                r += (v0 < key || (v0 == key && (j + 0) < i)) ? 1 : 0;
                r += (v1 < key || (v1 == key && (j + 1) < i)) ? 1 : 0;
                r += (v2 < key || (v2 == key && (j + 2) < i)) ? 1 : 0;
                r += (v3 < key || (v3 == key && (j + 3) < i)) ? 1 : 0;
            }
            for (; j < d; j++) {
                const int v = srclist[o + j];
                r += (v < key || (v == key && j < i)) ? 1 : 0;
            }
            tmp[o + r] = key;   // ranks are unique within the segment
        }
        for (int i = 0; i < d; i++) srclist[o + i] = tmp[o + i];
    }

    // ================= phase 0: y0 = node_feat @ W0 (round-0 LDS-staged) =====
    float acc[32];
    #pragma unroll
    for (int c = 0; c < 32; c++) acc[c] = 0.f;
    {
        const float* nf = node_feat + (size_t)g * NPG * FDIM;
        for (int kc = 0; kc < 4; kc++) {
            __syncthreads();   // Ybuf chunk reuse (also orders sort-tmp, kc=0)
            // stage [256 nodes x 32 k] coalesced into Ybuf (stride 33)
            #pragma unroll
            for (int i = 0; i < 8; i++) {
                int Fi = t + i * 256;
                int n  = Fi >> 3, k4 = Fi & 7;
                const float4 v = *(const float4*)(nf + n * FDIM + kc * 32 + k4 * 4);
                float* p = &Ybuf[n * 33 + k4 * 4];
                p[0] = v.x; p[1] = v.y; p[2] = v.z; p[3] = v.w;
            }
            __syncthreads();
            #pragma unroll
            for (int k = 0; k < 32; k++) {
                float h = Ybuf[t * 33 + k];                // bank (t+k)%32: conflict-free
                const float* wr = W0 + (kc * 32 + k) * 32; // wave-uniform -> scalar loads
                #pragma unroll
                for (int c = 0; c < 32; c++) acc[c] = fmaf(h, wr[c], acc[c]);
            }
        }
        __syncthreads();
        #pragma unroll
        for (int c = 0; c < 32; c++) Ybuf[t * 33 + c] = acc[c];
        __syncthreads();
    }

    // pooled = y[t] + sum_{in-edges} y[src]; 4 neighbors in flight (sorted
    // srclist order -> deterministic sums).
    auto agg = [&](float (&h)[32]) {
        const float* self = &Ybuf[t * 33];
        #pragma unroll
        for (int c = 0; c < 32; c++) h[c] = self[c];
        int j = 0;
        for (; j + 4 <= d; j += 4) {
            const int a0 = srclist[o + j + 0];
            const int a1 = srclist[o + j + 1];
            const int a2 = srclist[o + j + 2];
            const int a3 = srclist[o + j + 3];
            const float* r0 = &Ybuf[a0 * 33];
            const float* r1 = &Ybuf[a1 * 33];
            const float* r2 = &Ybuf[a2 * 33];
            const float* r3 = &Ybuf[a3 * 33];
            #pragma unroll
            for (int c = 0; c < 32; c++) h[c] += r0[c];
            #pragma unroll
            for (int c = 0; c < 32; c++) h[c] += r1[c];
            #pragma unroll
            for (int c = 0; c < 32; c++) h[c] += r2[c];
            #pragma unroll
            for (int c = 0; c < 32; c++) h[c] += r3[c];
        }
        for (; j < d; j++) {
            const float* yr = &Ybuf[srclist[o + j] * 33];
            #pragma unroll
            for (int c = 0; c < 32; c++) h[c] += yr[c];
        }
    };
    auto act = [&](float (&h)[32], const float* bb) {
        #pragma unroll
        for (int c = 0; c < 32; c++) h[c] = tanhf((h[c] + bb[c]) * iv);
    };
    // y_next = h @ Wn (32x32) -> Ybuf (barrier-protected overwrite)
    auto matml = [&](const float (&h)[32], const float* Wn) {
        float a[32];
        #pragma unroll
        for (int c = 0; c < 32; c++) a[c] = 0.f;
        #pragma unroll
        for (int k = 0; k < 32; k++) {
            const float* wr = Wn + k * 32;   // wave-uniform -> scalar loads
            const float  hk = h[k];
            #pragma unroll
            for (int c = 0; c < 32; c++) a[c] = fmaf(hk, wr[c], a[c]);
        }
        __syncthreads();   // all agg reads of Ybuf complete
        #pragma unroll
        for (int c = 0; c < 32; c++) Ybuf[t * 33 + c] = a[c];
        __syncthreads();
    };

    // ================= 4 GNN layers =================
    float h1[32], h2[32], h3[32];
    agg(h1); act(h1, b0); matml(h1, W1);
    agg(h2); act(h2, b1); matml(h2, W2);
    agg(h3); act(h3, b2);
    {   // layer 3 projection: y3 = h3 @ W3  (W3 is 32x1)
        float a3 = 0.f;
        #pragma unroll
        for (int k = 0; k < 32; k++) a3 = fmaf(h3[k], W3[k], a3);
        __syncthreads();   // all layer-2 agg reads of Ybuf complete
        Ybuf[t * 33] = a3;
        __syncthreads();
    }
    float kv;
    {   // layer 3 aggregate (1-wide) + activation -> sort key; 4-wide unroll
        float s = Ybuf[t * 33];
        int j = 0;
        for (; j + 4 <= d; j += 4) {
            const int a0 = srclist[o + j + 0];
            const int a1 = srclist[o + j + 1];
            const int a2 = srclist[o + j + 2];
            const int a3i = srclist[o + j + 3];
            s += Ybuf[a0 * 33];
            s += Ybuf[a1 * 33];
            s += Ybuf[a2 * 33];
            s += Ybuf[a3i * 33];
        }
        for (; j < d; j++) s += Ybuf[srclist[o + j] * 33];
        kv = tanhf((s + b3[0]) * iv);
        keys[t] = kv;
    }
    __syncthreads();

    // ================= sortpool: rank-based top-K (jax tie-break: lower idx) ==
    int rank = 0;
    #pragma unroll 4
    for (int j = 0; j < NPG; j++) {
        float vj = keys[j];
        rank += ((vj > kv) || ((vj == kv) && (j < t))) ? 1 : 0;
    }

    // ================= export selected Z rows + stage tail weights ===========
    float* sp    = (float*)srclist;   // 2910 floats (srclist dead from here)
    float* x1    = sp + 30 * 97;      // 480
    float* xp    = x1 + 480;          // 240
    float* dense = xp + 240;          // 352  (total 3982 floats <= 4096)

    if (rank < KTOP) {
        float* dp = sp + rank * 97;
        #pragma unroll
        for (int c = 0; c < 32; c++) dp[c]      = h1[c];
        #pragma unroll
        for (int c = 0; c < 32; c++) dp[32 + c] = h2[c];
        #pragma unroll
        for (int c = 0; c < 32; c++) dp[64 + c] = h3[c];
        dp[96] = kv;
    }
    // Ybuf is dead now -> stage conv weights into LDS (coalesced once) so the
    // deep conv loops read LDS instead of per-lane global gathers.
    float* wb1 = Ybuf;               // 1552 floats (16x97)
    float* wb2 = Ybuf + 1552;        // 2560 floats (32x16x5)
    float* wbo = Ybuf + 1552 + 2560; // 704 floats  (352x2)
    for (int i = t; i < 1552; i += 256) wb1[i] = cw1[i];
    for (int i = t; i < 2560; i += 256) wb2[i] = cw2[i];
    for (int i = t; i < 704;  i += 256) wbo[i] = ow[i];
    __syncthreads();

    // conv1: kernel width 97, stride 97 -> per-row dot; out [16][30], relu
    for (int idx = t; idx < 480; idx += 256) {
        int k = idx >> 4, c = idx & 15;
        float s = cb1[c];
        for (int dd = 0; dd < 97; dd++) s = fmaf(sp[k * 97 + dd], wb1[c * 97 + dd], s);
        x1[c * 30 + k] = fmaxf(s, 0.f);
    }
    __syncthreads();
    // maxpool1d(2,2) -> [16][15]
    for (int idx = t; idx < 240; idx += 256) {
        int c = idx / 15, k = idx - c * 15;
        xp[idx] = fmaxf(x1[c * 30 + 2 * k], x1[c * 30 + 2 * k + 1]);
    }
    __syncthreads();
    // conv2: [32][16][5] VALID over 15 -> [32][11], relu; dense idx = c*11+j
    for (int idx = t; idx < 352; idx += 256) {
        int c = idx / 11, j = idx - c * 11;
        float s = cb2[c];
        for (int i2 = 0; i2 < 16; i2++) {
            #pragma unroll
            for (int tt = 0; tt < 5; tt++)
                s = fmaf(xp[i2 * 15 + j + tt], wb2[(c * 16 + i2) * 5 + tt], s);
        }
        dense[idx] = fmaxf(s, 0.f);
    }
    __syncthreads();
    // output: relu(relu(dense @ out_w + out_b)) -> [2]
    if (t < 64) {
        float a0 = 0.f, a1 = 0.f;
        for (int dd = t; dd < 352; dd += 64) {
            float v = dense[dd];
            a0 = fmaf(v, wbo[dd * 2],     a0);
            a1 = fmaf(v, wbo[dd * 2 + 1], a1);
        }
        #pragma unroll
        for (int off2 = 32; off2 > 0; off2 >>= 1) {
            a0 += __shfl_down(a0, off2);
            a1 += __shfl_down(a1, off2);
        }
        if (t == 0) {
            outp[g * 2 + 0] = fmaxf(a0 + ob[0], 0.f);
            outp[g * 2 + 1] = fmaxf(a1 + ob[1], 0.f);
        }
    }
}

extern "C" void kernel_launch(void* const* d_in, const int* in_sizes, int n_in,
                              void* d_out, int out_size, void* d_ws, size_t ws_size,
                              hipStream_t stream) {
    const float* node_feat = (const float*)d_in[0];
    const int*   src       = (const int*)  d_in[1];
    const int*   dst       = (const int*)  d_in[2];
    const int*   degsp     = (const int*)  d_in[3];
    const float* W0 = (const float*)d_in[4];
    const float* b0 = (const float*)d_in[5];
    const float* W1 = (const float*)d_in[6];
    const float* b1 = (const float*)d_in[7];
    const float* W2 = (const float*)d_in[8];
    const float* b2 = (const float*)d_in[9];
    const float* W3 = (const float*)d_in[10];
    const float* b3 = (const float*)d_in[11];
    const float* cw1 = (const float*)d_in[12];
    const float* cb1 = (const float*)d_in[13];
    const float* cw2 = (const float*)d_in[14];
    const float* cb2 = (const float*)d_in[15];
    const float* ow  = (const float*)d_in[16];
    const float* ob  = (const float*)d_in[17];

    dgcnn_fused<<<dim3(256), dim3(256), 0, stream>>>(
        node_feat, src, dst, degsp,
        W0, b0, W1, b1, W2, b2, W3, b3,
        cw1, cb1, cw2, cb2, ow, ob, (float*)d_out);
}